// Round 5
// baseline (232.179 us; speedup 1.0000x reference)
//
#include <hip/hip_runtime.h>
#include <hip/hip_bf16.h>

#define FH 200
#define FW 200
#define FC 1024
#define POOL 7
#define NPOW 512   // next pow2 >= N (N=300)

typedef float vf4 __attribute__((ext_vector_type(4)));

__device__ __forceinline__ vf4 lerp4(vf4 a, vf4 b, float w1) {
    return a * (1.0f - w1) + b * w1;
}

// Kernel A: sort ROI indices by spatial tile of origin so that temporally
// adjacent blocks in kernel B touch overlapping feature pixels (L2/L3 reuse).
__global__ __launch_bounds__(NPOW) void sort_rois_kernel(
    const int* __restrict__ rois, unsigned* __restrict__ order, int N)
{
    __shared__ unsigned s[NPOW];
    const int tid = threadIdx.x;

    unsigned packed = 0xFFFFFFFFu;
    if (tid < N) {
        const int x0 = rois[4 * tid + 0];
        const int y0 = rois[4 * tid + 1];
        const unsigned key = (unsigned)((y0 >> 4) * 8 + (x0 >> 4)); // 16x16 tiles
        packed = (key << 16) | (unsigned)tid;
    }
    s[tid] = packed;
    __syncthreads();

    for (int k = 2; k <= NPOW; k <<= 1) {
        for (int j = k >> 1; j > 0; j >>= 1) {
            const int ixj = tid ^ j;
            if (ixj > tid) {
                const unsigned a = s[tid], b = s[ixj];
                const bool up = ((tid & k) == 0);
                if ((a > b) == up) { s[tid] = b; s[ixj] = a; }
            }
            __syncthreads();
        }
    }
    if (tid < N) order[tid] = s[tid] & 0xFFFFu;
}

// Kernel B: one block per (sorted_n, py, px). 256 threads x float4 = 1024 ch.
// Wave-uniform branches skip weight-0 loads (px==0 -> fx==0, py==0 -> fy==0).
__global__ __launch_bounds__(256) void roi_pool_kernel(
    const float* __restrict__ feat,      // (H, W, C)
    const int*   __restrict__ rois,      // (N, 4) = x0, y0, w, h
    const unsigned* __restrict__ order,  // spatially sorted ROI indices
    float*       __restrict__ out,       // (N, POOL, POOL, C)
    int N)
{
    const int blk = blockIdx.x;
    const int ns  = blk / (POOL * POOL);   // sorted position
    if (ns >= N) return;
    const int n   = (int)order[ns];        // actual ROI index
    const int r   = blk % (POOL * POOL);
    const int py  = r / POOL;
    const int px  = r % POOL;

    const int x0 = rois[4 * n + 0];
    const int y0 = rois[4 * n + 1];
    const int w  = rois[4 * n + 2];
    const int h  = rois[4 * n + 3];

    // Match reference arithmetic order exactly (fp32 throughout).
    const float ry = (float)py * ((float)h / (float)POOL);
    const float rx = (float)px * ((float)w / (float)POOL);
    const int ylo = (int)floorf(ry);
    const int xlo = (int)floorf(rx);
    const float fy = ry - (float)ylo;
    const float fx = rx - (float)xlo;
    const int yhi = min(ylo + 1, h - 1);
    const int xhi = min(xlo + 1, w - 1);

    const int iy0 = min(max(y0 + ylo, 0), FH - 1);
    const int iy1 = min(max(y0 + yhi, 0), FH - 1);
    const int ix0 = min(max(x0 + xlo, 0), FW - 1);
    const int ix1 = min(max(x0 + xhi, 0), FW - 1);

    const int t = threadIdx.x;
    const vf4* p00 = (const vf4*)(feat + ((size_t)iy0 * FW + ix0) * FC);
    const vf4* p01 = (const vf4*)(feat + ((size_t)iy0 * FW + ix1) * FC);
    const vf4* p10 = (const vf4*)(feat + ((size_t)iy1 * FW + ix0) * FC);
    const vf4* p11 = (const vf4*)(feat + ((size_t)iy1 * FW + ix1) * FC);

    const bool needX = (fx != 0.0f);   // wave-uniform
    const bool needY = (fy != 0.0f);   // wave-uniform

    vf4 a, b, c, d;
    a = p00[t];
    if (needX) b = p01[t];
    if (needY) c = p10[t];
    if (needX && needY) d = p11[t];

    vf4 top = needX ? lerp4(a, b, fx) : a;
    vf4 res;
    if (needY) {
        vf4 bot = needX ? lerp4(c, d, fx) : c;
        res = lerp4(top, bot, fy);
    } else {
        res = top;
    }

    // Output goes to the ORIGINAL ROI slot.
    float* o = out + ((size_t)n * (POOL * POOL) + r) * FC + 4 * t;
    __builtin_nontemporal_store(res, (vf4*)o);
}

extern "C" void kernel_launch(void* const* d_in, const int* in_sizes, int n_in,
                              void* d_out, int out_size, void* d_ws, size_t ws_size,
                              hipStream_t stream) {
    const float* feat = (const float*)d_in[0];   // (1, 200, 200, 1024) fp32
    const int*   rois = (const int*)d_in[1];     // (300, 4) int32
    float* out = (float*)d_out;                  // (300, 7, 7, 1024) fp32
    unsigned* order = (unsigned*)d_ws;           // 300 x u32 scratch

    const int N = in_sizes[1] / 4;
    sort_rois_kernel<<<1, NPOW, 0, stream>>>(rois, order, N);
    const int blocks = N * POOL * POOL;
    roi_pool_kernel<<<blocks, 256, 0, stream>>>(feat, rois, order, out, N);
}

// Round 6
// 225.372 us; speedup vs baseline: 1.0302x; 1.0302x over previous
//
#include <hip/hip_runtime.h>
#include <hip/hip_bf16.h>

#define FH 200
#define FW 200
#define FC 1024
#define POOL 7

typedef float vf4 __attribute__((ext_vector_type(4)));

__device__ __forceinline__ vf4 lerp4(vf4 a, vf4 b, float w1) {
    return a * (1.0f - w1) + b * w1;
}

// One block per (n, py, px). 256 threads x float4 = 1024 channels.
// Wave-uniform branches skip weight-0 loads (px==0 -> fx==0, py==0 -> fy==0):
// avg 3.45 loads/position instead of 4 (-13.8% issued reads; paid back at
// ~HBM rate in round 4). ROI reordering (round 5) was tested and regressed:
// within-run repeats already hit L3 (issued ~207 MB, unique ~126 MB < 256 MiB).
__global__ __launch_bounds__(256) void roi_pool_kernel(
    const float* __restrict__ feat,   // (H, W, C)
    const int*   __restrict__ rois,   // (N, 4) = x0, y0, w, h
    float*       __restrict__ out,    // (N, POOL, POOL, C)
    int N)
{
    const int blk = blockIdx.x;
    const int n  = blk / (POOL * POOL);
    if (n >= N) return;
    const int r  = blk % (POOL * POOL);
    const int py = r / POOL;
    const int px = r % POOL;

    const int x0 = rois[4 * n + 0];
    const int y0 = rois[4 * n + 1];
    const int w  = rois[4 * n + 2];
    const int h  = rois[4 * n + 3];

    // Match reference arithmetic order exactly (fp32 throughout).
    const float ry = (float)py * ((float)h / (float)POOL);
    const float rx = (float)px * ((float)w / (float)POOL);
    const int ylo = (int)floorf(ry);
    const int xlo = (int)floorf(rx);
    const float fy = ry - (float)ylo;
    const float fx = rx - (float)xlo;
    const int yhi = min(ylo + 1, h - 1);
    const int xhi = min(xlo + 1, w - 1);

    const int iy0 = min(max(y0 + ylo, 0), FH - 1);
    const int iy1 = min(max(y0 + yhi, 0), FH - 1);
    const int ix0 = min(max(x0 + xlo, 0), FW - 1);
    const int ix1 = min(max(x0 + xhi, 0), FW - 1);

    const int t = threadIdx.x;
    const vf4* p00 = (const vf4*)(feat + ((size_t)iy0 * FW + ix0) * FC);
    const vf4* p01 = (const vf4*)(feat + ((size_t)iy0 * FW + ix1) * FC);
    const vf4* p10 = (const vf4*)(feat + ((size_t)iy1 * FW + ix0) * FC);
    const vf4* p11 = (const vf4*)(feat + ((size_t)iy1 * FW + ix1) * FC);

    const bool needX = (fx != 0.0f);   // wave-uniform
    const bool needY = (fy != 0.0f);   // wave-uniform

    // Issue every needed load before any compute.
    vf4 a, b, c, d;
    a = p00[t];
    if (needX) b = p01[t];
    if (needY) c = p10[t];
    if (needX && needY) d = p11[t];

    vf4 top = needX ? lerp4(a, b, fx) : a;
    vf4 res;
    if (needY) {
        vf4 bot = needX ? lerp4(c, d, fx) : c;
        res = lerp4(top, bot, fy);
    } else {
        res = top;
    }

    float* o = out + ((size_t)blk) * FC + 4 * t;
    __builtin_nontemporal_store(res, (vf4*)o);
}

extern "C" void kernel_launch(void* const* d_in, const int* in_sizes, int n_in,
                              void* d_out, int out_size, void* d_ws, size_t ws_size,
                              hipStream_t stream) {
    const float* feat = (const float*)d_in[0];   // (1, 200, 200, 1024) fp32
    const int*   rois = (const int*)d_in[1];     // (300, 4) int32
    float* out = (float*)d_out;                  // (300, 7, 7, 1024) fp32

    const int N = in_sizes[1] / 4;
    const int blocks = N * POOL * POOL;
    roi_pool_kernel<<<blocks, 256, 0, stream>>>(feat, rois, out, N);
}